// Round 1
// baseline (83.308 us; speedup 1.0000x reference)
//
#include <hip/hip_runtime.h>
#include <hip/hip_bf16.h>

// Problem constants
#define NN    32
#define CC    49
#define HWSZ  81
#define MSZ   24
#define KSZ   7
#define PADSZ 3
#define NHW   (NN*HWSZ)     // 2592
#define NCHW  (NN*CC*HWSZ)  // 127008

// o-grouping: each block handles OPB consecutive o's, accumulating the o-sum
// in MFMA accumulator registers. Grid = (OGRP, NN) = (8, 32) = 256 blocks.
#define OPB   3
#define OGRP  (MSZ/OPB)     // 8

// LDS strides (in shorts / bf16 elements). All row strides * 2B are multiples
// of 16B (b128-aligned fragment loads). Total LDS = 13312+13312+13824+9216
// = 49664 B. One 512-thread block per CU (256 blocks on 256 CUs).
#define XSB_S  104   // xsb[64][104]  : x[n] as bf16 (pads zeroed surgically)
#define MSK_S  104   // msk[64][104]  : mask rows dd (fully zero-filled)
#define MSKT_S 72    // mskT[96][72]  : mask transposed (fully zero-filled)
#define G_S    72    // gm[64][72]    : leaky(fk)[c][dd] (fully overwritten/o)

typedef __attribute__((ext_vector_type(8))) short short8;
typedef __attribute__((ext_vector_type(4))) short short4v;
typedef __attribute__((ext_vector_type(4))) float f32x4;

__device__ __forceinline__ short f2b(float v) {
    unsigned u = __float_as_uint(v);
    u += 0x7fffu + ((u >> 16) & 1u);      // round-to-nearest-even to bf16
    return (short)(u >> 16);
}
__device__ __forceinline__ float b2f(short s) {
    return __uint_as_float(((unsigned)(unsigned short)s) << 16);
}

// Kernel 1: one block (512 thr = 8 waves) per (n, o-group of 3).
//   phase A (once): stage x->xsb + surgical pad-zero + full msk/mskT zero.
//   per o in group:
//     phase B: conv(K=7 over channel)+softmax(81) from xsb; 8 waves x 4 rows
//              x 2 iters cover dd=0..63 (dd<49 live). Softmax WITHOUT
//              max-subtraction: |logit| <= ~14 -> exp <= ~1.3e6, sum <= ~1e8,
//              safe in fp32.
//     phase C: MFMA fkT[dd][c] = msk(64x96).xsb^T -> leaky -> gm[c][dd].
//              16 (mt,nt) tile pairs over 8 waves (2 each).
//     phase D: MFMA out_partial[c][hw] = gm(64x64).mskT^T, ACCUMULATED into
//              persistent dacc[3] (C-in = C-out across ks AND o). 24 (ct,nt)
//              tile pairs over 8 waves (3 each).
//   epilogue: fp32 atomicAdd of dacc into out[n] (masked c<49, hw<81);
//             ~3969 atomics/block, 1.02M total, 8-way/address contention.
// NaN-safety: every LDS word an MFMA reads is real data or explicit 0.
__global__ __launch_bounds__(512) void fuse_k1(
    const float* __restrict__ x, const float* __restrict__ cw,
    const float* __restrict__ cb, float* __restrict__ acc)
{
    __shared__ short xsb [64 * XSB_S];    // 13312 B
    __shared__ short msk [64 * MSK_S];    // 13312 B
    __shared__ short mskT[96 * MSKT_S];   // 13824 B
    __shared__ short gm  [64 * G_S];      //  9216 B

    const int og = blockIdx.x;         // 0..7  (o-group)
    const int n  = blockIdx.y;         // 0..31
    const int t  = threadIdx.x;        // 0..511
    const int lane = t & 63;
    const int wv = t >> 6;             // 0..7
    const int lr = lane & 15;
    const int lq = lane >> 4;          // quad index 0..3

    const float* xg = x + (size_t)n * CC * HWSZ;

    // ---- phase A: all writes disjoint (once per block) ----
    const f32x4 z4 = {0.f, 0.f, 0.f, 0.f};
    // (a) stage x[n] data into xsb rows 0-48, cols 0-80
    for (int i = t; i < CC * HWSZ; i += 512) {
        int c = i / HWSZ, hw = i - c * HWSZ;
        xsb[c * XSB_S + hw] = f2b(xg[i]);
    }
    // (b) xsb pad cols 81..103 of rows 0-48 (scalar 81-87, b128 88-103)
    if (t < CC) {
        short* row = xsb + t * XSB_S;
        #pragma unroll
        for (int cq = 81; cq < 88; ++cq) row[cq] = 0;
        *(f32x4*)(row + 88) = z4;
        *(f32x4*)(row + 96) = z4;
    }
    // (c) xsb rows 49-63 full zero (15 rows x 13 b128-groups)
    for (int j = t; j < 15 * 13; j += 512) {
        int rr = j / 13, cg = j - rr * 13;
        *(f32x4*)(xsb + (49 + rr) * XSB_S + cg * 8) = z4;
    }
    // (d) msk / mskT full zero
    for (int i = t; i < 832; i += 512) ((f32x4*)msk)[i] = z4;
    for (int i = t; i < 864; i += 512) ((f32x4*)mskT)[i] = z4;
    __syncthreads();

    // Wave -> tile assignments (constant per thread)
    const int mt   = wv & 3;           // phase C: dd-tile (M)
    const int ntc0 = (wv >> 2) * 2;    // phase C: first c-tile (N), 2 per wave
    const int ct   = wv & 3;           // phase D: c-tile (M)
    const int nh   = (wv >> 2) * 3;    // phase D: first hw-tile (N), 3 per wave

    f32x4 dacc[3];
    #pragma unroll
    for (int j = 0; j < 3; ++j) dacc[j] = z4;

    for (int oo = 0; oo < OPB; ++oo) {
        const int o = og * OPB + oo;
        float wk[KSZ];
        #pragma unroll
        for (int k = 0; k < KSZ; ++k) wk[k] = cw[o * KSZ + k];
        const float bias = cb[o];

        // ---- phase B: conv + softmax (no max-sub); rows dd = it*32+wv*4+lq.
        // Lane lr covers cols [4lr,4lr+4) (b64), col 64+lr, and col 80 on lr==0.
        #pragma unroll
        for (int it = 0; it < 2; ++it) {
            int dd = it * 32 + wv * 4 + lq;
            if (dd < CC) {
                float a0 = 0.f, a1 = 0.f, a2 = 0.f, a3 = 0.f, a4 = 0.f, a5 = 0.f;
                #pragma unroll
                for (int k = 0; k < KSZ; ++k) {
                    int r = dd + k - PADSZ;
                    if (r >= 0 && r < CC) {
                        const short* xr = xsb + r * XSB_S;
                        short4v xa = *(const short4v*)(xr + 4 * lr);
                        float w = wk[k];
                        a0 += w * b2f(xa[0]);
                        a1 += w * b2f(xa[1]);
                        a2 += w * b2f(xa[2]);
                        a3 += w * b2f(xa[3]);
                        a4 += w * b2f(xr[64 + lr]);
                        if (lr == 0) a5 += w * b2f(xr[80]);
                    }
                }
                float e0 = __expf(a0 + bias), e1 = __expf(a1 + bias);
                float e2 = __expf(a2 + bias), e3 = __expf(a3 + bias);
                float e4 = __expf(a4 + bias);
                float e5 = (lr == 0) ? __expf(a5 + bias) : 0.f;
                float s = ((e0 + e1) + (e2 + e3)) + (e4 + e5);
                #pragma unroll
                for (int off = 8; off; off >>= 1) s += __shfl_xor(s, off, 64);
                float inv = __builtin_amdgcn_rcpf(s);
                short4v pk;
                pk[0] = f2b(e0 * inv); pk[1] = f2b(e1 * inv);
                pk[2] = f2b(e2 * inv); pk[3] = f2b(e3 * inv);
                short b4 = f2b(e4 * inv);
                short* mrow = msk + dd * MSK_S;
                *(short4v*)(mrow + 4 * lr) = pk;        // b64, 8B-aligned
                mrow[64 + lr] = b4;
                mskT[(4 * lr    ) * MSKT_S + dd] = pk[0];
                mskT[(4 * lr + 1) * MSKT_S + dd] = pk[1];
                mskT[(4 * lr + 2) * MSKT_S + dd] = pk[2];
                mskT[(4 * lr + 3) * MSKT_S + dd] = pk[3];
                mskT[(64 + lr   ) * MSKT_S + dd] = b4;
                if (lr == 0) {
                    short b5 = f2b(e5 * inv);
                    mrow[80] = b5;
                    mskT[80 * MSKT_S + dd] = b5;
                }
            }
        }
        __syncthreads();

        // ---- phase C (MFMA): fkT[dd][c] = sum_hw msk[dd][hw] * xsb[c][hw]
        // M=dd tile mt, N=c tiles ntc0..ntc0+1, K=hw (96, 3 steps).
        {
            short8 a2f[3];
            #pragma unroll
            for (int ks = 0; ks < 3; ++ks)
                a2f[ks] = *(const short8*)&msk[(mt * 16 + lr) * MSK_S + ks * 32 + lq * 8];
            #pragma unroll
            for (int jn = 0; jn < 2; ++jn) {
                int nt = ntc0 + jn;
                f32x4 accv = {0.f, 0.f, 0.f, 0.f};
                #pragma unroll
                for (int ks = 0; ks < 3; ++ks) {
                    short8 b = *(const short8*)&xsb[(nt * 16 + lr) * XSB_S + ks * 32 + lq * 8];
                    accv = __builtin_amdgcn_mfma_f32_16x16x32_bf16(a2f[ks], b, accv, 0, 0, 0);
                }
                // C-layout: lane holds fkT[dd = mt*16 + lq*4 + r][c = nt*16 + lr]
                short4v pk;
                #pragma unroll
                for (int r = 0; r < 4; ++r) {
                    float v = accv[r];
                    v = (v >= 0.f) ? v : 0.01f * v;
                    pk[r] = f2b(v);
                }
                *(short4v*)&gm[(nt * 16 + lr) * G_S + mt * 16 + lq * 4] = pk;
            }
        }
        __syncthreads();

        // ---- phase D (MFMA): out_partial[c][hw] = sum_dd gm[c][dd]*mskT[hw][dd]
        // M=c tile ct, N=hw tiles nh..nh+2, K=dd (64, 2 steps).
        // dacc[j] accumulates across ks AND across the o-loop (C-in == C-out).
        {
            short8 a1f[2];
            #pragma unroll
            for (int ks = 0; ks < 2; ++ks)
                a1f[ks] = *(const short8*)&gm[(ct * 16 + lr) * G_S + ks * 32 + lq * 8];
            #pragma unroll
            for (int j = 0; j < 3; ++j) {
                int nt = nh + j;
                #pragma unroll
                for (int ks = 0; ks < 2; ++ks) {
                    short8 b = *(const short8*)&mskT[(nt * 16 + lr) * MSKT_S + ks * 32 + lq * 8];
                    dacc[j] = __builtin_amdgcn_mfma_f32_16x16x32_bf16(a1f[ks], b, dacc[j], 0, 0, 0);
                }
            }
        }
        __syncthreads();   // D reads done before next o's B/C overwrite LDS
    }

    // ---- epilogue: fp32 atomic accumulation into out[n] ----
    float* dstn = acc + (size_t)n * CC * HWSZ;
    #pragma unroll
    for (int j = 0; j < 3; ++j) {
        int hw = (nh + j) * 16 + lr;
        if (hw < HWSZ) {
            int c0 = ct * 16 + lq * 4;
            #pragma unroll
            for (int r = 0; r < 4; ++r) {
                int c = c0 + r;
                if (c < CC) atomicAdd(dstn + c * HWSZ + hw, dacc[j][r]);
            }
        }
    }
}

// Kernel 2: residual add + batch-norm in-place on d_out (which holds the
// fp32 o-summed partials). Reads 1 MB contiguous fp32, writes 508 KB.
__global__ __launch_bounds__(1024) void fuse_k2(
    float* __restrict__ out, const float* __restrict__ x,
    const float* __restrict__ gamma, const float* __restrict__ beta)
{
    const int c = blockIdx.x;
    const int t = threadIdx.x;
    float vals[3];
    float sum = 0.f, sq = 0.f;
    int cnt = 0;
    for (int i = t; i < NHW; i += 1024) {
        int n = i / HWSZ;
        int hw = i - n * HWSZ;
        int idx = (n * CC + c) * HWSZ + hw;
        float v = out[idx] + x[idx];
        vals[cnt++] = v;
        sum += v; sq += v * v;
    }
    #pragma unroll
    for (int off = 32; off; off >>= 1) {
        sum += __shfl_xor(sum, off, 64);
        sq  += __shfl_xor(sq, off, 64);
    }
    __shared__ float rs[16], rq[16];
    const int lane = t & 63, wv = t >> 6;
    if (lane == 0) { rs[wv] = sum; rq[wv] = sq; }
    __syncthreads();
    float ts = 0.f, tq = 0.f;
    #pragma unroll
    for (int w = 0; w < 16; ++w) { ts += rs[w]; tq += rq[w]; }
    const float invD = 1.f / (float)NHW;
    float mean = ts * invD;
    float var  = tq * invD - mean * mean;
    float scal = rsqrtf(var + 1e-5f) * gamma[c];
    float shft = beta[c] - mean * scal;
    cnt = 0;
    for (int i = t; i < NHW; i += 1024) {
        int n = i / HWSZ;
        int hw = i - n * HWSZ;
        out[(n * CC + c) * HWSZ + hw] = vals[cnt++] * scal + shft;
    }
}

extern "C" void kernel_launch(void* const* d_in, const int* in_sizes, int n_in,
                              void* d_out, int out_size, void* d_ws, size_t ws_size,
                              hipStream_t stream) {
    const float* x     = (const float*)d_in[0];
    const float* cw    = (const float*)d_in[1];
    const float* cb    = (const float*)d_in[2];
    const float* gamma = (const float*)d_in[3];
    const float* beta  = (const float*)d_in[4];
    float* out = (float*)d_out;

    // No workspace usage at all: accumulate fp32 partials directly into out.
    hipMemsetAsync(out, 0, (size_t)NCHW * sizeof(float), stream);
    fuse_k1<<<dim3(OGRP, NN), 512, 0, stream>>>(x, cw, cb, out);
    fuse_k2<<<CC, 1024, 0, stream>>>(out, x, gamma, beta);
}